// Round 11
// baseline (2141.411 us; speedup 1.0000x reference)
//
#include <hip/hip_runtime.h>

#define BATCH 16
#define CH    64
#define LEN   4096
#define NCODE 1024
#define NPTS  (BATCH * LEN)          // 65536
#define MT    128                    // points per block (2 per lane)
#define NW    8                      // waves per block = code slices
#define CPW   (NCODE / NW)           // 128 codes per wave
#define CG    16                     // codes per group (one s_load_dwordx16)
#define NGRP  (CPW / CG)             // 8 groups
#define NPART (NPTS / MT)            // 512 partials

typedef float float2v __attribute__((ext_vector_type(2)));

// ---------------------------------------------------------------------------
// Kernel 1 (prep): cbt[c][k] = cb[k][c]  and  w2[k] = sum_c cb[k][c]^2.
// ---------------------------------------------------------------------------
__global__ __launch_bounds__(256) void vq_prep(const float* __restrict__ cb,
                                               float* __restrict__ cbt,
                                               float* __restrict__ w2) {
    __shared__ float tile[64][65];
    const int k0 = blockIdx.x * 64;
    const int t  = threadIdx.x;
#pragma unroll
    for (int r = 0; r < 16; ++r) {
        int idx = r * 256 + t;            // over 64 codes x 64 ch
        int k = idx >> 6, c = idx & 63;
        tile[k][c] = cb[(size_t)(k0 + k) * CH + c];
    }
    __syncthreads();
#pragma unroll
    for (int r = 0; r < 16; ++r) {
        int idx = r * 256 + t;
        int c = idx >> 6, k = idx & 63;   // write coalesced in k
        cbt[(size_t)c * NCODE + k0 + k] = tile[k][c];
    }
    if (t < 64) {
        float s = 0.f;
#pragma unroll
        for (int c = 0; c < CH; ++c) s = fmaf(tile[t][c], tile[t][c], s);
        w2[k0 + t] = s;
    }
}

// ---------------------------------------------------------------------------
// Kernel 2: argmin, scalar-codebook / global-x hybrid.
// 512 thr = 8 waves; wave = one 128-code slice; lane owns 2 points.
// Per channel step: 1 global_load_dwordx2 (x, vmcnt domain, L1/L2-hot 32KB
// tile) + 1 s_load_dwordx16 (w, lgkmcnt domain -> no DS/SMEM mixing) +
// 32 v_fmac_f32 acc,s,v  (94% VALU density; r8's hybrid had 8).
// Zero LDS in the hot loop -> LDS-BW roofline (r7/r10's 125us wall) gone.
// Only acc[2][16] (static idx) lives across iters -> RA-safe (r2-6 lesson).
// ---------------------------------------------------------------------------
__global__ __launch_bounds__(512, 4) void vq_argmin(const float*  __restrict__ x,
                                                    const float*  __restrict__ cbt,
                                                    const float*  __restrict__ w2,
                                                    float*        __restrict__ idx_out,
                                                    double*       __restrict__ partial) {
    __shared__ float  sb0[NW * 64], sb1[NW * 64];
    __shared__ int    sk0[NW * 64], sk1[NW * 64];
    __shared__ double ssum[64];

    const int t    = threadIdx.x;
    const int lane = t & 63;
    const int wv   = __builtin_amdgcn_readfirstlane(t >> 6);   // 0..7, scalar
    const int p0   = blockIdx.x * MT;
    const int b    = p0 >> 12;          // / LEN
    const int l0   = p0 & (LEN - 1);

    // per-lane base into x[b][:][l0 + 2*lane]
    const float* xb = x + (size_t)b * CH * LEN + l0 + 2 * lane;

    // |x|^2 for my 2 points (also warms L1 with the block's 32KB x-tile)
    float x2a = 0.f, x2b = 0.f;
#pragma unroll
    for (int c = 0; c < CH; ++c) {
        float2v v = *(const float2v*)(xb + (size_t)c * LEN);
        x2a = fmaf(v.x, v.x, x2a);
        x2b = fmaf(v.y, v.y, x2b);
    }

    const float* __restrict__ wp  = cbt + wv * CPW;   // scalar base, cbt[c][k]
    const float* __restrict__ w2p = w2 + wv * CPW;    // scalar base

    float best0 = 3.4e38f, best1 = 3.4e38f;
    int   bk0 = 0, bk1 = 0;

    for (int g = 0; g < NGRP; ++g) {
        float acc0[CG], acc1[CG];
#pragma unroll
        for (int j = 0; j < CG; ++j) { acc0[j] = 0.f; acc1[j] = 0.f; }

#pragma unroll
        for (int c = 0; c < CH; ++c) {
            float2v xa = *(const float2v*)(xb + (size_t)c * LEN);   // dwordx2
            const float* wr = wp + (size_t)c * NCODE + g * CG;      // scalar
#pragma unroll
            for (int j = 0; j < CG; ++j) {
                acc0[j] = fmaf(xa.x, wr[j], acc0[j]);   // v_fmac v,s,v
                acc1[j] = fmaf(xa.y, wr[j], acc1[j]);
            }
        }

        // cost = w2[k] - 2*dot  (x2 is constant per point -> same argmin,
        // same ascending-k strict-< first-occurrence tie-break)
#pragma unroll
        for (int j = 0; j < CG; ++j) {
            int   k   = g * CG + j;
            float w2k = w2p[k];
            float c0  = fmaf(-2.0f, acc0[j], w2k);
            float c1  = fmaf(-2.0f, acc1[j], w2k);
            if (c0 < best0) { best0 = c0; bk0 = k; }
            if (c1 < best1) { best1 = c1; bk1 = k; }
        }
    }
    bk0 += wv * CPW;
    bk1 += wv * CPW;

    sb0[wv * 64 + lane] = best0;  sk0[wv * 64 + lane] = bk0;
    sb1[wv * 64 + lane] = best1;  sk1[wv * 64 + lane] = bk1;
    __syncthreads();

    if (wv == 0) {
        // merge slices in ascending order (strict < keeps lowest k on ties)
#pragma unroll
        for (int s = 1; s < NW; ++s) {
            float ob0 = sb0[s * 64 + lane];
            int   ok0 = sk0[s * 64 + lane];
            if (ob0 < best0) { best0 = ob0; bk0 = ok0; }
            float ob1 = sb1[s * 64 + lane];
            int   ok1 = sk1[s * 64 + lane];
            if (ob1 < best1) { best1 = ob1; bk1 = ok1; }
        }
        float2v iv; iv.x = (float)bk0; iv.y = (float)bk1;
        *(float2v*)(idx_out + p0 + 2 * lane) = iv;
        // min d2 = x2 + (w2 - 2*dot)
        ssum[lane] = ((double)x2a + (double)best0) + ((double)x2b + (double)best1);
    }
    __syncthreads();

    if (t == 0) {
        double s = 0.0;
        for (int i = 0; i < 64; ++i) s += ssum[i];
        partial[blockIdx.x] = s;
    }
}

// ---------------------------------------------------------------------------
// Kernel 3: quant_out[b,c,l] = codebook[idx[b,l], c]  (coalesced writes)
// ---------------------------------------------------------------------------
__global__ __launch_bounds__(256) void vq_gather(const float* __restrict__ cbk,
                                                 const float* __restrict__ idx_f,
                                                 float*       __restrict__ out) {
    int t  = blockIdx.x * 256 + threadIdx.x;   // over B*C*L
    int l  = t & (LEN - 1);
    int bc = t >> 12;
    int c  = bc & (CH - 1);
    int b  = bc >> 6;
    int k  = (int)idx_f[b * LEN + l];
    out[t] = cbk[(size_t)k * CH + c];
}

// ---------------------------------------------------------------------------
// Kernel 4: final loss reduction over the NPART per-block partials.
// ---------------------------------------------------------------------------
__global__ __launch_bounds__(256) void vq_loss(const double* __restrict__ partial,
                                               float*        __restrict__ losses) {
    __shared__ double sred[256];
    double v = 0.0;
#pragma unroll
    for (int i = 0; i < NPART / 256; ++i) v += partial[threadIdx.x + 256 * i];
    sred[threadIdx.x] = v;
    __syncthreads();
    for (int s = 128; s > 0; s >>= 1) {
        if (threadIdx.x < s) sred[threadIdx.x] += sred[threadIdx.x + s];
        __syncthreads();
    }
    if (threadIdx.x == 0) {
        float loss = (float)(sred[0] / (double)((size_t)NPTS * CH));
        losses[0] = loss;   // codebook_loss
        losses[1] = loss;   // commitment_loss (same value)
    }
}

// ---------------------------------------------------------------------------
extern "C" void kernel_launch(void* const* d_in, const int* in_sizes, int n_in,
                              void* d_out, int out_size, void* d_ws, size_t ws_size,
                              hipStream_t stream) {
    const float* x  = (const float*)d_in[0];   // (B, C, L)
    const float* cb = (const float*)d_in[1];   // (K, C)
    float* out = (float*)d_out;

    // d_out layout: [quant_out (B*C*L)] [codebook_loss] [commitment_loss] [indices (B*L)]
    float* quant_out = out;
    float* losses    = out + (size_t)BATCH * CH * LEN;
    float* idx_out   = losses + 2;

    // ws: [0,8KB) double partials; [8KB,12KB) w2; [16KB,16KB+256KB) cbt
    double* partial = (double*)d_ws;
    float*  w2      = (float*)((char*)d_ws + 8192);
    float*  cbt     = (float*)((char*)d_ws + 16384);

    vq_prep<<<NCODE / 64, 256, 0, stream>>>(cb, cbt, w2);
    vq_argmin<<<NPTS / MT, 512, 0, stream>>>(x, cbt, w2, idx_out, partial);
    vq_gather<<<(BATCH * CH * LEN) / 256, 256, 0, stream>>>(cb, idx_out, quant_out);
    vq_loss<<<1, 256, 0, stream>>>(partial, losses);
}